// Round 1
// baseline (226.786 us; speedup 1.0000x reference)
//
#include <hip/hip_runtime.h>
#include <math.h>

#define PI_F 3.14159265358979323846f

// Problem constants: x (8,1,2048,2048) fp32 -> out (8,16,128,128) fp32
// Patches: 16x16, D_in=256, D=16, 131072 patches total (16384 per batch).

// Workspace float offsets
#define WS_M     0      // M[16][256]
#define WS_V     4096   // v[16]
#define WS_A     4352   // A[16][256]
#define WS_U     8448   // u[16]
#define WS_STATS 8464   // sum[64], sumsq[64]

// ---------------------------------------------------------------------------
// prep1: M[m][n] = (1/64) Re( sum_k e^{-2pi i k n/256} * T[m][k] )
//        T[m][k] = sum_d Wc[d][k] e^{+2pi i d m/16},  Wc = wr + i*wi
//        v[m]    = (1/4)  Re( sum_d (br[d]+i*bi[d]) e^{+2pi i d m/16} )
// grid: 16 blocks (m), 256 threads (k then n)
// ---------------------------------------------------------------------------
__global__ void prep1(const float* __restrict__ wr, const float* __restrict__ wi,
                      const float* __restrict__ br, const float* __restrict__ bi,
                      float* __restrict__ M, float* __restrict__ v) {
    const int m = blockIdx.x;
    const int t = threadIdx.x;
    __shared__ float Tr[256], Ti[256], cosT[256], sinT[256], cd[16], sd[16];

    float ang = (2.0f * PI_F / 256.0f) * (float)t;
    cosT[t] = cosf(ang);
    sinT[t] = sinf(ang);
    if (t < 16) {
        float a = (2.0f * PI_F / 16.0f) * (float)((t * m) & 15);
        cd[t] = cosf(a);
        sd[t] = sinf(a);
    }
    __syncthreads();

    // T[m][k], k = t
    float tr = 0.f, ti = 0.f;
    #pragma unroll
    for (int d = 0; d < 16; ++d) {
        float wrv = wr[d * 256 + t];
        float wiv = wi[d * 256 + t];
        tr += wrv * cd[d] - wiv * sd[d];
        ti += wrv * sd[d] + wiv * cd[d];
    }
    Tr[t] = tr;
    Ti[t] = ti;
    __syncthreads();

    // M[m][n], n = t : Re(T * e^{-i theta}) = Tr cos + Ti sin
    float acc = 0.f;
    for (int k = 0; k < 256; ++k) {
        int a = (k * t) & 255;
        acc += Tr[k] * cosT[a] + Ti[k] * sinT[a];
    }
    M[m * 256 + t] = acc * (1.0f / 64.0f);

    if (t == 0) {
        float s = 0.f;
        #pragma unroll
        for (int d = 0; d < 16; ++d) {
            float a = (2.0f * PI_F / 16.0f) * (float)((d * m) & 15);
            s += br[d] * cosf(a) - bi[d] * sinf(a);
        }
        v[m] = 0.25f * s;
    }
}

// ---------------------------------------------------------------------------
// prep2: A = conv_w @ M, u = conv_w @ v + conv_b; zero GN stats.
// 1 block, 256 threads (n = t)
// ---------------------------------------------------------------------------
__global__ void prep2(const float* __restrict__ conv_w, const float* __restrict__ conv_b,
                      const float* __restrict__ M, const float* __restrict__ v,
                      float* __restrict__ A, float* __restrict__ u,
                      float* __restrict__ stats) {
    const int t = threadIdx.x;
    __shared__ float cw[256];
    __shared__ float Ms[16][256];
    cw[t] = conv_w[t];
    #pragma unroll
    for (int m = 0; m < 16; ++m) Ms[m][t] = M[m * 256 + t];
    __syncthreads();

    #pragma unroll
    for (int e = 0; e < 16; ++e) {
        float acc = 0.f;
        #pragma unroll
        for (int m = 0; m < 16; ++m) acc += cw[e * 16 + m] * Ms[m][t];
        A[e * 256 + t] = acc;
    }
    if (t < 16) {
        float acc = conv_b[t];
        #pragma unroll
        for (int m = 0; m < 16; ++m) acc += cw[t * 16 + m] * v[m];
        u[t] = acc;
    }
    if (t < 128) stats[t] = 0.f;
}

// ---------------------------------------------------------------------------
// main: one thread per patch. out_pre = A @ p + u, write to d_out,
// accumulate per-(b,group) sum/sumsq into ws stats.
// grid: 512 blocks x 256 threads (block = 256 consecutive patches, one batch)
// ---------------------------------------------------------------------------
__global__ __launch_bounds__(256) void main_k(const float* __restrict__ x,
                                              const float* __restrict__ ws,
                                              float* __restrict__ out,
                                              float* __restrict__ stats) {
    __shared__ float As[4096];
    __shared__ float Us[16];
    __shared__ float s_sum[8], s_ssq[8];
    const int t = threadIdx.x;

    const float4* Ag  = (const float4*)(ws + WS_A);
    float4*       As4 = (float4*)As;
    #pragma unroll
    for (int i = 0; i < 4; ++i) As4[t + 256 * i] = Ag[t + 256 * i];
    if (t < 16) Us[t] = ws[WS_U + t];
    if (t < 8) { s_sum[t] = 0.f; s_ssq[t] = 0.f; }
    __syncthreads();

    const int P  = (blockIdx.x << 8) + t;   // patch id
    const int b  = P >> 14;                 // batch
    const int pi = P & 16383;
    const int ph = pi >> 7;
    const int pw = pi & 127;

    const float* xb = x + ((size_t)b << 22) + (size_t)(ph * 16) * 2048 + (size_t)(pw * 16);

    float acc[16];
    #pragma unroll
    for (int e = 0; e < 16; ++e) acc[e] = 0.f;

    for (int s1 = 0; s1 < 16; ++s1) {
        const float4* rp = (const float4*)(xb + (size_t)s1 * 2048);
        float4 p0 = rp[0], p1 = rp[1], p2 = rp[2], p3 = rp[3];
        const int nb = s1 << 4;
        #pragma unroll
        for (int e = 0; e < 16; ++e) {
            const float* Ae = As + (e << 8) + nb;
            const float4 a0 = *(const float4*)(Ae + 0);
            const float4 a1 = *(const float4*)(Ae + 4);
            const float4 a2 = *(const float4*)(Ae + 8);
            const float4 a3 = *(const float4*)(Ae + 12);
            acc[e] += a0.x * p0.x + a0.y * p0.y + a0.z * p0.z + a0.w * p0.w
                    + a1.x * p1.x + a1.y * p1.y + a1.z * p1.z + a1.w * p1.w
                    + a2.x * p2.x + a2.y * p2.y + a2.z * p2.z + a2.w * p2.w
                    + a3.x * p3.x + a3.y * p3.y + a3.z * p3.z + a3.w * p3.w;
        }
    }

    // bias + store + per-group stats
    float sv[8], qv[8];
    const size_t obase = ((size_t)b << 18) + (size_t)(ph << 7) + (size_t)pw;
    #pragma unroll
    for (int g = 0; g < 8; ++g) {
        float v0 = acc[2 * g]     + Us[2 * g];
        float v1 = acc[2 * g + 1] + Us[2 * g + 1];
        out[obase + (size_t)(2 * g) * 16384]     = v0;
        out[obase + (size_t)(2 * g + 1) * 16384] = v1;
        sv[g] = v0 + v1;
        qv[g] = v0 * v0 + v1 * v1;
    }
    #pragma unroll
    for (int off = 32; off > 0; off >>= 1) {
        #pragma unroll
        for (int g = 0; g < 8; ++g) {
            sv[g] += __shfl_xor(sv[g], off, 64);
            qv[g] += __shfl_xor(qv[g], off, 64);
        }
    }
    if ((t & 63) == 0) {
        #pragma unroll
        for (int g = 0; g < 8; ++g) {
            atomicAdd(&s_sum[g], sv[g]);
            atomicAdd(&s_ssq[g], qv[g]);
        }
    }
    __syncthreads();
    if (t < 8) {
        atomicAdd(&stats[b * 8 + t],      s_sum[t]);
        atomicAdd(&stats[64 + b * 8 + t], s_ssq[t]);
    }
}

// ---------------------------------------------------------------------------
// finalize: in-place GroupNorm on d_out using accumulated stats.
// grid: 2048 blocks x 256 threads, float4 per thread
// ---------------------------------------------------------------------------
__global__ __launch_bounds__(256) void finalize(float* __restrict__ out,
                                                const float* __restrict__ stats,
                                                const float* __restrict__ gamma,
                                                const float* __restrict__ beta) {
    const int i    = blockIdx.x * 256 + threadIdx.x;  // float4 index
    const int flat = i << 2;
    const int b = flat >> 18;
    const int c = (flat >> 14) & 15;
    const int g = c >> 1;

    const float inv_n = 1.0f / 32768.0f;
    float mean = stats[b * 8 + g] * inv_n;
    float var  = stats[64 + b * 8 + g] * inv_n - mean * mean;
    float rstd = rsqrtf(var + 1e-5f);
    float sc = rstd * gamma[c];
    float sh = beta[c] - mean * sc;

    float4 vv = ((float4*)out)[i];
    vv.x = vv.x * sc + sh;
    vv.y = vv.y * sc + sh;
    vv.z = vv.z * sc + sh;
    vv.w = vv.w * sc + sh;
    ((float4*)out)[i] = vv;
}

extern "C" void kernel_launch(void* const* d_in, const int* in_sizes, int n_in,
                              void* d_out, int out_size, void* d_ws, size_t ws_size,
                              hipStream_t stream) {
    const float* x  = (const float*)d_in[0];
    const float* wr = (const float*)d_in[1];
    const float* wi = (const float*)d_in[2];
    const float* br = (const float*)d_in[3];
    const float* bi = (const float*)d_in[4];
    const float* cw = (const float*)d_in[5];
    const float* cb = (const float*)d_in[6];
    const float* gm = (const float*)d_in[7];
    const float* bt = (const float*)d_in[8];
    float* out = (float*)d_out;
    float* ws  = (float*)d_ws;

    prep1<<<16, 256, 0, stream>>>(wr, wi, br, bi, ws + WS_M, ws + WS_V);
    prep2<<<1, 256, 0, stream>>>(cw, cb, ws + WS_M, ws + WS_V,
                                 ws + WS_A, ws + WS_U, ws + WS_STATS);
    main_k<<<512, 256, 0, stream>>>(x, ws, out, ws + WS_STATS);
    finalize<<<2048, 256, 0, stream>>>(out, ws + WS_STATS, gm, bt);
}